// Round 9
// baseline (1122.759 us; speedup 1.0000x reference)
//
#include <hip/hip_runtime.h>
#include <hip/hip_fp16.h>

// DNCClassifier: DNC memory machinery is dead code (inputs built with the
// initial zero read vector); output = LSTM-final-h @ W_fc.T + b_fc.
//   gates_t = x_t @ W_ih[:, :27].T + (b_ih + b_hh) + h @ W_hh.T
// Sizes: B=128, T=512, IN=27, H=256 (4H=1024), OUT=128.
//
// R9: R8 fit the 65536-VGPR/WG budget (VGPR=116, no demotion) and exposed
// the true wall: the 28-quad L2 stream tier ran at 53 B/cyc/CU == the
// per-CU share of the 34.5 TB/s L2 ceiling (step 4310 cyc, pure L2-bound).
// Fix: replace the L2 tier with AGPR storage (unified file half unused by
// the budget law; R1 proved AGPRs are granted beyond it). AGPR read cost =
// 512 B/cyc/CU, 9x the L2 path. asm "+a" pins make demotion impossible.
//   wave w (0..7): half = w>>2 (K-half), u = (w&3)*64 + lane.
//   64 weight quads/thread, f = 4*jq + g (jq = h-quad 0..15, g = gate):
//     f  0..17 VGPR  (72 regs)
//     f 18..33 LDS   (131 KB, ~1540 cyc/step @ 85 B/cyc)
//     f 34..63 AGPR  (120 AGPRs, reads on VALU pipe)
//   h via v_readlane from per-wave snapshot (wave-uniform half).
// Step ~= max(VALU ~1950, LDS ~1540) + 2 barriers ~= 2200 cyc.

typedef _Float16 h2t __attribute__((ext_vector_type(2)));
typedef unsigned int u32x4 __attribute__((ext_vector_type(4)));

#if defined(__has_builtin)
#  if __has_builtin(__builtin_amdgcn_fdot2)
#    define HAVE_FDOT2 1
#  endif
#endif

__device__ __forceinline__ h2t bc2(unsigned int v) {
  union { unsigned int u; h2t h; } x; x.u = v; return x.h;
}
__device__ __forceinline__ unsigned int pk(float a, float b) {
  union { h2t h; unsigned int u; } x;
  x.h[0] = (_Float16)a; x.h[1] = (_Float16)b;
  return x.u;
}
__device__ __forceinline__ float fdot2f(h2t a, h2t b, float c) {
#ifdef HAVE_FDOT2
  return __builtin_amdgcn_fdot2(a, b, c, false);
#else
  return c + (float)a[0] * (float)b[0] + (float)a[1] * (float)b[1];
#endif
}
__device__ __forceinline__ float dot4s(u32x4 w, unsigned h0, unsigned h1,
                                       unsigned h2, unsigned h3, float a) {
  a = fdot2f(bc2(w[0]), bc2(h0), a);
  a = fdot2f(bc2(w[1]), bc2(h1), a);
  a = fdot2f(bc2(w[2]), bc2(h2), a);
  a = fdot2f(bc2(w[3]), bc2(h3), a);
  return a;
}
__device__ __forceinline__ float dot4d(unsigned w0, unsigned w1, unsigned w2,
                                       unsigned w3, unsigned h0, unsigned h1,
                                       unsigned h2, unsigned h3, float a) {
  a = fdot2f(bc2(w0), bc2(h0), a);
  a = fdot2f(bc2(w1), bc2(h1), a);
  a = fdot2f(bc2(w2), bc2(h2), a);
  a = fdot2f(bc2(w3), bc2(h3), a);
  return a;
}
__device__ __forceinline__ float sigmf_(float x) {
  return 1.f / (1.f + __expf(-x));
}
__device__ __forceinline__ float tanhf_(float x) {
  float xc = fminf(15.f, fmaxf(-15.f, x));
  float e = __expf(2.f * xc);
  return (e - 1.f) / (e + 1.f);
}

// ---- workspace layout (bytes) ----
// P : [(t*128+b)*256+u] uint2 (gates i,f,g,o fp16, bias folded in) - 128 MB
// W : u32x4[f*512 + v], f = 0..63 - 512 KB, coalesced 16 B/lane per f-row
#define WS_P_OFF 0ull
#define WS_W_OFF 134217728ull
#define WS_NEED  134742016ull

__global__ void prep_w(const float* __restrict__ W_hh,
                       unsigned char* __restrict__ ws) {
  int j = blockIdx.x * 256 + threadIdx.x;  // dword id, 512 blocks -> j < 131072
  int e = j & 3, v = (j >> 2) & 511, f = j >> 11;
  int jq = f >> 2, g = f & 3;
  int w = v >> 6, l = v & 63;
  int half = w >> 2;
  int u = ((w & 3) << 6) + l;
  int k2 = 64 * half + 4 * jq + e;
  int r = g * 256 + u;
  ((unsigned int*)(ws + WS_W_OFF))[j] =
      pk(W_hh[r * 256 + 2 * k2], W_hh[r * 256 + 2 * k2 + 1]);
}

// P[t,b,u,:] = bias(u,:) + x[b,t,:27] @ W_ih[:, :27].T  (fp16x4 out)
__global__ __launch_bounds__(256) void prep_p(const float* __restrict__ x,
                                              const float* __restrict__ W_ih,
                                              const float* __restrict__ b_ih,
                                              const float* __restrict__ b_hh,
                                              unsigned char* __restrict__ ws) {
  __shared__ unsigned int sX[64][14];
  const int u = threadIdx.x;
  const int t = blockIdx.x >> 1;
  const int b0 = (blockIdx.x & 1) << 6;
  unsigned int wih[4][14];
  float bias[4];
#pragma unroll
  for (int g = 0; g < 4; ++g) {
    const float* row = W_ih + (size_t)(g * 256 + u) * 47;
    bias[g] = b_ih[g * 256 + u] + b_hh[g * 256 + u];
#pragma unroll
    for (int j = 0; j < 14; ++j) {
      float a = row[2 * j];
      float b = (2 * j + 1 < 27) ? row[2 * j + 1] : 0.f;
      wih[g][j] = pk(a, b);
    }
  }
#pragma unroll 1
  for (int j = u; j < 896; j += 256) {        // stage 64 rows of x
    int row = j / 14, c2 = j - 14 * row;
    const float* xr = x + ((size_t)(b0 + row) * 512 + t) * 27;
    float a = xr[2 * c2];
    float bb = (2 * c2 + 1 < 27) ? xr[2 * c2 + 1] : 0.f;
    sX[row][c2] = pk(a, bb);
  }
  __syncthreads();
  uint2* Pout = (uint2*)(ws + WS_P_OFF);
#pragma unroll 2
  for (int p = 0; p < 64; ++p) {
    float a0 = bias[0], a1 = bias[1], a2 = bias[2], a3 = bias[3];
#pragma unroll
    for (int j = 0; j < 14; ++j) {
      h2t xx = bc2(sX[p][j]);
      a0 = fdot2f(bc2(wih[0][j]), xx, a0);
      a1 = fdot2f(bc2(wih[1][j]), xx, a1);
      a2 = fdot2f(bc2(wih[2][j]), xx, a2);
      a3 = fdot2f(bc2(wih[3][j]), xx, a3);
    }
    uint2 o; o.x = pk(a0, a1); o.y = pk(a2, a3);
    Pout[((size_t)t * 128 + (b0 + p)) * 256 + u] = o;
  }
}

#define RL(k) ((unsigned)__builtin_amdgcn_readlane((int)hrs, (k)))
#define JH(j, W0, W1, W2, W3)                                  \
  {                                                            \
    unsigned h0 = RL(4 * (j) + 0), h1 = RL(4 * (j) + 1);       \
    unsigned h2 = RL(4 * (j) + 2), h3 = RL(4 * (j) + 3);       \
    acc0 = dot4s(W0, h0, h1, h2, h3, acc0);                    \
    acc1 = dot4s(W1, h0, h1, h2, h3, acc1);                    \
    acc2 = dot4s(W2, h0, h1, h2, h3, acc2);                    \
    acc3 = dot4s(W3, h0, h1, h2, h3, acc3);                    \
  }
// AGPR-tier jq-block: gates 0..3 from AGPR quads fa..fa+3
#define JHA(j, fa)                                                           \
  {                                                                          \
    unsigned h0 = RL(4 * (j) + 0), h1 = RL(4 * (j) + 1);                     \
    unsigned h2 = RL(4 * (j) + 2), h3 = RL(4 * (j) + 3);                     \
    acc0 = dot4d(wa[(fa)*4+0], wa[(fa)*4+1], wa[(fa)*4+2], wa[(fa)*4+3],     \
                 h0, h1, h2, h3, acc0);                                      \
    acc1 = dot4d(wa[(fa)*4+4], wa[(fa)*4+5], wa[(fa)*4+6], wa[(fa)*4+7],     \
                 h0, h1, h2, h3, acc1);                                      \
    acc2 = dot4d(wa[(fa)*4+8], wa[(fa)*4+9], wa[(fa)*4+10], wa[(fa)*4+11],   \
                 h0, h1, h2, h3, acc2);                                      \
    acc3 = dot4d(wa[(fa)*4+12], wa[(fa)*4+13], wa[(fa)*4+14], wa[(fa)*4+15], \
                 h0, h1, h2, h3, acc3);                                      \
  }

// Persistent LSTM scan. grid=128 (one block per batch element), 512 threads.
__global__ __launch_bounds__(512) void scan_k(
    const unsigned char* __restrict__ ws, const float* __restrict__ W_fc,
    const float* __restrict__ b_fc, float* __restrict__ out) {
  __shared__ u32x4 sW[16 * 512];               // 131,072 B LDS weight tier
  __shared__ float4 sRed[2][256];              // 8 KB K-half partial exchange
  __shared__ unsigned int sHd[128];            // h as 128 h2 dwords
  __shared__ float sHF[256];                   // final h fp32 for head
  const int v = threadIdx.x, b = blockIdx.x;
  const int w = v >> 6, l = v & 63;
  const int half = w >> 2;                     // wave-uniform K-half
  const int u = ((w & 3) << 6) + l;
  const bool upd = (half == 0);
  const u32x4* Wq = (const u32x4*)(ws + WS_W_OFF);

  // tier 1: VGPR weights (18 quads = 72 regs, under the 128 budget)
  u32x4 wr[18];
#pragma unroll
  for (int f = 0; f < 18; ++f) wr[f] = Wq[f * 512 + v];
  // tier 2: LDS weights (16 quads = 131 KB)
#pragma unroll
  for (int f = 0; f < 16; ++f) sW[f * 512 + v] = Wq[(18 + f) * 512 + v];
  // tier 3: AGPR weights (30 quads = 120 AGPRs), pinned with "a" constraints
  // so the allocator can neither rematerialize nor demote them.
  unsigned wa[120];
#pragma unroll
  for (int f = 0; f < 30; ++f) {
    u32x4 tq = Wq[(34 + f) * 512 + v];
    wa[4 * f + 0] = tq[0]; wa[4 * f + 1] = tq[1];
    wa[4 * f + 2] = tq[2]; wa[4 * f + 3] = tq[3];
    asm volatile("" : "+a"(wa[4 * f + 0]), "+a"(wa[4 * f + 1]),
                      "+a"(wa[4 * f + 2]), "+a"(wa[4 * f + 3]));
  }
  if (v < 128) sHd[v] = 0u;                    // h_0 = 0

  const uint2* Pbuf = (const uint2*)(ws + WS_P_OFF);
  uint2 pP = make_uint2(0u, 0u);
  if (upd) pP = Pbuf[(size_t)b * 256 + u];
  float c = 0.f, hval = 0.f;
  __syncthreads();
  unsigned hrs = sHd[(half << 6) + l];         // lane d holds h2 dword 64*half+d

#pragma unroll 1
  for (int t = 0; t < 512; ++t) {
    float acc0 = 0.f, acc1 = 0.f, acc2 = 0.f, acc3 = 0.f;
    JH(0, wr[0], wr[1], wr[2], wr[3]);
    JH(1, wr[4], wr[5], wr[6], wr[7]);
    JH(2, wr[8], wr[9], wr[10], wr[11]);
    JH(3, wr[12], wr[13], wr[14], wr[15]);
    JH(4, wr[16], wr[17], sW[0 * 512 + v], sW[1 * 512 + v]);
    JH(5, sW[2 * 512 + v], sW[3 * 512 + v], sW[4 * 512 + v], sW[5 * 512 + v]);
    JH(6, sW[6 * 512 + v], sW[7 * 512 + v], sW[8 * 512 + v], sW[9 * 512 + v]);
    JH(7, sW[10 * 512 + v], sW[11 * 512 + v], sW[12 * 512 + v], sW[13 * 512 + v]);
    {  // jq=8: f=32,33 LDS; f=34,35 AGPR (fa 0,1)
      unsigned h0 = RL(32), h1 = RL(33), h2 = RL(34), h3 = RL(35);
      acc0 = dot4s(sW[14 * 512 + v], h0, h1, h2, h3, acc0);
      acc1 = dot4s(sW[15 * 512 + v], h0, h1, h2, h3, acc1);
      acc2 = dot4d(wa[0], wa[1], wa[2], wa[3], h0, h1, h2, h3, acc2);
      acc3 = dot4d(wa[4], wa[5], wa[6], wa[7], h0, h1, h2, h3, acc3);
    }
    JHA(9, 2);
    JHA(10, 6);
    JHA(11, 10);
    JHA(12, 14);
    JHA(13, 18);
    JHA(14, 22);
    JHA(15, 26);

    if (!upd) sRed[t & 1][u] = make_float4(acc0, acc1, acc2, acc3);
    __syncthreads();                           // partials visible

    if (upd) {
      float4 o = sRed[t & 1][u];
      h2t p01 = bc2(pP.x), p23 = bc2(pP.y);
      float gi = acc0 + o.x + (float)p01[0];
      float gf = acc1 + o.y + (float)p01[1];
      float gg = acc2 + o.z + (float)p23[0];
      float go = acc3 + o.w + (float)p23[1];
      c = sigmf_(gf) * c + sigmf_(gi) * tanhf_(gg);
      hval = sigmf_(go) * tanhf_(c);
      ((unsigned short*)sHd)[u] = (unsigned short)(pk(hval, 0.f) & 0xffffu);
      if (t == 511) sHF[u] = hval;
      int tn = (t < 511) ? t + 1 : 511;
      pP = Pbuf[((size_t)tn * 128 + b) * 256 + u];
    }
    __syncthreads();                           // h_{t+1} visible
    hrs = sHd[(half << 6) + l];                // refresh snapshot
  }

  // --- classifier head on final h (sHF covered by last barrier) ---
  if (v < 128) {
    const float4* wrow = (const float4*)(W_fc + (size_t)v * 256);
    float a = b_fc[v];
#pragma unroll 8
    for (int q = 0; q < 64; ++q) {
      float4 wv = wrow[q];
      float4 hh = ((const float4*)sHF)[q];
      a += wv.x * hh.x + wv.y * hh.y + wv.z * hh.z + wv.w * hh.w;
    }
    out[(size_t)b * 128 + v] = a;
  }
}

extern "C" void kernel_launch(void* const* d_in, const int* in_sizes, int n_in,
                              void* d_out, int out_size, void* d_ws,
                              size_t ws_size, hipStream_t stream) {
  const float* x    = (const float*)d_in[0];
  // d_in[1] = input_lengths: unused by the reference
  const float* W_ih = (const float*)d_in[2];
  const float* W_hh = (const float*)d_in[3];
  const float* b_ih = (const float*)d_in[4];
  const float* b_hh = (const float*)d_in[5];
  // d_in[6] = W_xi, d_in[7] = b_xi: dead code in the reference
  const float* W_fc = (const float*)d_in[8];
  const float* b_fc = (const float*)d_in[9];
  unsigned char* ws = (unsigned char*)d_ws;

  if (ws_size < WS_NEED) return;  // signature: output stays poisoned

  prep_w<<<512, 256, 0, stream>>>(W_hh, ws);
  prep_p<<<1024, 256, 0, stream>>>(x, W_ih, b_ih, b_hh, ws);
  scan_k<<<128, 512, 0, stream>>>(ws, W_fc, b_fc, (float*)d_out);
}

// Round 10
// 913.269 us; speedup vs baseline: 1.2294x; 1.2294x over previous
//
#include <hip/hip_runtime.h>
#include <hip/hip_fp16.h>

// DNCClassifier: DNC memory machinery is dead code (inputs built with the
// initial zero read vector); output = LSTM-final-h @ W_fc.T + b_fc.
//   gates_t = x_t @ W_ih[:, :27].T + (b_ih + b_hh) + h @ W_hh.T
// Sizes: B=128, T=512, IN=27, H=256 (4H=1024), OUT=128.
//
// R10: consistent model of R6/R8/R9:
//  - R6 (52 demoted quads -> L2 reloads): 16 CU/XCD x 425 KB = 6.8 MB/step
//    / 1800 B/cyc per-XCD L2 = 3780 cyc == measured 3825. L2-BOUND.
//    Its VALU busy (~2600) fits 2-cyc dot2.
//  - R8 (tiering cut L2 to 229 KB -> 2040 cyc) was masked by the readlane
//    h-tier (64/thread + SGPR hazards -> busy ~3100). VALU-BOUND.
//  - R9 AGPR tier: +accvgpr_read per use -> worse. Rejected.
// Fix: combine R8's tiering with R6's h-distribution. h is read as
// wave-uniform ds_read_b128 (LDS broadcast: 1 access serves 64 lanes).
//   wave w (0..7): half = w>>2 (K-half), u = (w&3)*64 + lane.
//   64 weight quads/thread, f = 4*jq + g (jq = h-quad 0..15, g = gate):
//     f  0..17 VGPR (72 regs)  | f 18..35 LDS (147 KB, ~1730 cyc/step)
//     f 36..63 L2-streamed (229 KB/step/CU -> ~2040 cyc/step per-XCD L2)
// Step ~= max(L2 2040, LDS 1730, VALU ~1350) + barriers ~= 2400 cyc.

typedef _Float16 h2t __attribute__((ext_vector_type(2)));
typedef unsigned int u32x4 __attribute__((ext_vector_type(4)));

#if defined(__has_builtin)
#  if __has_builtin(__builtin_amdgcn_fdot2)
#    define HAVE_FDOT2 1
#  endif
#endif

__device__ __forceinline__ h2t bc2(unsigned int v) {
  union { unsigned int u; h2t h; } x; x.u = v; return x.h;
}
__device__ __forceinline__ unsigned int pk(float a, float b) {
  union { h2t h; unsigned int u; } x;
  x.h[0] = (_Float16)a; x.h[1] = (_Float16)b;
  return x.u;
}
__device__ __forceinline__ float fdot2f(h2t a, h2t b, float c) {
#ifdef HAVE_FDOT2
  return __builtin_amdgcn_fdot2(a, b, c, false);
#else
  return c + (float)a[0] * (float)b[0] + (float)a[1] * (float)b[1];
#endif
}
__device__ __forceinline__ float dot4(u32x4 w, u32x4 h, float a) {
  a = fdot2f(bc2(w[0]), bc2(h[0]), a);
  a = fdot2f(bc2(w[1]), bc2(h[1]), a);
  a = fdot2f(bc2(w[2]), bc2(h[2]), a);
  a = fdot2f(bc2(w[3]), bc2(h[3]), a);
  return a;
}
__device__ __forceinline__ float sigmf_(float x) {
  return 1.f / (1.f + __expf(-x));
}
__device__ __forceinline__ float tanhf_(float x) {
  float xc = fminf(15.f, fmaxf(-15.f, x));
  float e = __expf(2.f * xc);
  return (e - 1.f) / (e + 1.f);
}

// ---- workspace layout (bytes) ----
// P : [(t*128+b)*256+u] uint2 (gates i,f,g,o fp16, bias folded in) - 128 MB
// W : u32x4[f*512 + v], f = 0..63 - 512 KB, coalesced 16 B/lane per f-row
#define WS_P_OFF 0ull
#define WS_W_OFF 134217728ull
#define WS_NEED  134742016ull

__global__ void prep_w(const float* __restrict__ W_hh,
                       unsigned char* __restrict__ ws) {
  int j = blockIdx.x * 256 + threadIdx.x;  // dword id, 512 blocks -> j < 131072
  int e = j & 3, v = (j >> 2) & 511, f = j >> 11;
  int jq = f >> 2, g = f & 3;
  int w = v >> 6, l = v & 63;
  int half = w >> 2;
  int u = ((w & 3) << 6) + l;
  int k2 = 64 * half + 4 * jq + e;
  int r = g * 256 + u;
  ((unsigned int*)(ws + WS_W_OFF))[j] =
      pk(W_hh[r * 256 + 2 * k2], W_hh[r * 256 + 2 * k2 + 1]);
}

// P[t,b,u,:] = bias(u,:) + x[b,t,:27] @ W_ih[:, :27].T  (fp16x4 out)
__global__ __launch_bounds__(256) void prep_p(const float* __restrict__ x,
                                              const float* __restrict__ W_ih,
                                              const float* __restrict__ b_ih,
                                              const float* __restrict__ b_hh,
                                              unsigned char* __restrict__ ws) {
  __shared__ unsigned int sX[64][14];
  const int u = threadIdx.x;
  const int t = blockIdx.x >> 1;
  const int b0 = (blockIdx.x & 1) << 6;
  unsigned int wih[4][14];
  float bias[4];
#pragma unroll
  for (int g = 0; g < 4; ++g) {
    const float* row = W_ih + (size_t)(g * 256 + u) * 47;
    bias[g] = b_ih[g * 256 + u] + b_hh[g * 256 + u];
#pragma unroll
    for (int j = 0; j < 14; ++j) {
      float a = row[2 * j];
      float b = (2 * j + 1 < 27) ? row[2 * j + 1] : 0.f;
      wih[g][j] = pk(a, b);
    }
  }
#pragma unroll 1
  for (int j = u; j < 896; j += 256) {        // stage 64 rows of x
    int row = j / 14, c2 = j - 14 * row;
    const float* xr = x + ((size_t)(b0 + row) * 512 + t) * 27;
    float a = xr[2 * c2];
    float bb = (2 * c2 + 1 < 27) ? xr[2 * c2 + 1] : 0.f;
    sX[row][c2] = pk(a, bb);
  }
  __syncthreads();
  uint2* Pout = (uint2*)(ws + WS_P_OFF);
#pragma unroll 2
  for (int p = 0; p < 64; ++p) {
    float a0 = bias[0], a1 = bias[1], a2 = bias[2], a3 = bias[3];
#pragma unroll
    for (int j = 0; j < 14; ++j) {
      h2t xx = bc2(sX[p][j]);
      a0 = fdot2f(bc2(wih[0][j]), xx, a0);
      a1 = fdot2f(bc2(wih[1][j]), xx, a1);
      a2 = fdot2f(bc2(wih[2][j]), xx, a2);
      a3 = fdot2f(bc2(wih[3][j]), xx, a3);
    }
    uint2 o; o.x = pk(a0, a1); o.y = pk(a2, a3);
    Pout[((size_t)t * 128 + (b0 + p)) * 256 + u] = o;
  }
}

// one jq-block: broadcast ds_read of h quad (wave-uniform address) + 4 dots
#define JHB(jq, W0, W1, W2, W3)        \
  {                                    \
    u32x4 hq = rd[jq];                 \
    acc0 = dot4(W0, hq, acc0);         \
    acc1 = dot4(W1, hq, acc1);         \
    acc2 = dot4(W2, hq, acc2);         \
    acc3 = dot4(W3, hq, acc3);         \
  }

// Persistent LSTM scan. grid=128 (one block per batch element), 512 threads.
__global__ __launch_bounds__(512) void scan_k(
    const unsigned char* __restrict__ ws, const float* __restrict__ W_fc,
    const float* __restrict__ b_fc, float* __restrict__ out) {
  __shared__ u32x4 sW[18 * 512];               // 147,456 B LDS weight tier
  __shared__ u32x4 sHq[2][32];                 // h double buffer (128 h2)
  __shared__ float4 sRed[256];                 // 4 KB K-half partial exchange
  __shared__ float sHF[256];                   // final h fp32 for head
  const int v = threadIdx.x, b = blockIdx.x;
  const int w = v >> 6, l = v & 63;
  const int half = w >> 2;                     // wave-uniform K-half
  const int u = ((w & 3) << 6) + l;
  const bool upd = (half == 0);
  const u32x4* Wq = (const u32x4*)(ws + WS_W_OFF);

  // tier 1: VGPR weights (18 quads = 72 regs, under the 128 budget)
  u32x4 wr[18];
#pragma unroll
  for (int f = 0; f < 18; ++f) wr[f] = Wq[f * 512 + v];
  // tier 2: LDS weights (18 quads = 147 KB)
#pragma unroll
  for (int f = 0; f < 18; ++f) sW[f * 512 + v] = Wq[(18 + f) * 512 + v];
  if (v < 64) {
    u32x4 z = {0u, 0u, 0u, 0u};
    ((u32x4*)sHq)[v] = z;                      // both h buffers = 0
  }

  const uint2* Pbuf = (const uint2*)(ws + WS_P_OFF);
  uint2 pP = make_uint2(0u, 0u);
  if (upd) pP = Pbuf[(size_t)b * 256 + u];
  float c = 0.f, hval = 0.f;
  __syncthreads();

#pragma unroll 1
  for (int t = 0; t < 512; ++t) {
    // tier-3 stream: 2-batch rolling pipeline, 8 quads (32 regs) in flight
    u32x4 sa0 = Wq[36 * 512 + v], sa1 = Wq[37 * 512 + v];
    u32x4 sa2 = Wq[38 * 512 + v], sa3 = Wq[39 * 512 + v];
    u32x4 sb0 = Wq[40 * 512 + v], sb1 = Wq[41 * 512 + v];
    u32x4 sb2 = Wq[42 * 512 + v], sb3 = Wq[43 * 512 + v];

    const u32x4* rd = &sHq[t & 1][half << 4];  // broadcast reads (uniform addr)
    float acc0 = 0.f, acc1 = 0.f, acc2 = 0.f, acc3 = 0.f;
    JHB(0, wr[0], wr[1], wr[2], wr[3]);
    JHB(1, wr[4], wr[5], wr[6], wr[7]);
    JHB(2, wr[8], wr[9], wr[10], wr[11]);
    JHB(3, wr[12], wr[13], wr[14], wr[15]);
    JHB(4, wr[16], wr[17], sW[0 * 512 + v], sW[1 * 512 + v]);
    JHB(5, sW[2 * 512 + v], sW[3 * 512 + v], sW[4 * 512 + v], sW[5 * 512 + v]);
    JHB(6, sW[6 * 512 + v], sW[7 * 512 + v], sW[8 * 512 + v], sW[9 * 512 + v]);
    JHB(7, sW[10 * 512 + v], sW[11 * 512 + v], sW[12 * 512 + v], sW[13 * 512 + v]);
    JHB(8, sW[14 * 512 + v], sW[15 * 512 + v], sW[16 * 512 + v], sW[17 * 512 + v]);
    JHB(9, sa0, sa1, sa2, sa3);
    sa0 = Wq[44 * 512 + v]; sa1 = Wq[45 * 512 + v];
    sa2 = Wq[46 * 512 + v]; sa3 = Wq[47 * 512 + v];
    JHB(10, sb0, sb1, sb2, sb3);
    sb0 = Wq[48 * 512 + v]; sb1 = Wq[49 * 512 + v];
    sb2 = Wq[50 * 512 + v]; sb3 = Wq[51 * 512 + v];
    JHB(11, sa0, sa1, sa2, sa3);
    sa0 = Wq[52 * 512 + v]; sa1 = Wq[53 * 512 + v];
    sa2 = Wq[54 * 512 + v]; sa3 = Wq[55 * 512 + v];
    JHB(12, sb0, sb1, sb2, sb3);
    sb0 = Wq[56 * 512 + v]; sb1 = Wq[57 * 512 + v];
    sb2 = Wq[58 * 512 + v]; sb3 = Wq[59 * 512 + v];
    JHB(13, sa0, sa1, sa2, sa3);
    sa0 = Wq[60 * 512 + v]; sa1 = Wq[61 * 512 + v];
    sa2 = Wq[62 * 512 + v]; sa3 = Wq[63 * 512 + v];
    JHB(14, sb0, sb1, sb2, sb3);
    JHB(15, sa0, sa1, sa2, sa3);

    if (!upd) sRed[u] = make_float4(acc0, acc1, acc2, acc3);
    __syncthreads();                           // partials visible; h reads done

    if (upd) {
      float4 o = sRed[u];
      h2t p01 = bc2(pP.x), p23 = bc2(pP.y);
      float gi = acc0 + o.x + (float)p01[0];
      float gf = acc1 + o.y + (float)p01[1];
      float gg = acc2 + o.z + (float)p23[0];
      float go = acc3 + o.w + (float)p23[1];
      c = sigmf_(gf) * c + sigmf_(gi) * tanhf_(gg);
      hval = sigmf_(go) * tanhf_(c);
      ((_Float16*)(&sHq[(t + 1) & 1][0]))[u] = (_Float16)hval;
      if (t == 511) sHF[u] = hval;
      int tn = (t < 511) ? t + 1 : 511;
      pP = Pbuf[((size_t)tn * 128 + b) * 256 + u];
    }
    __syncthreads();                           // h_{t+1} visible; sRed reusable
  }

  // --- classifier head on final h (sHF covered by last barrier) ---
  if (v < 128) {
    const float4* wrow = (const float4*)(W_fc + (size_t)v * 256);
    float a = b_fc[v];
#pragma unroll 8
    for (int q = 0; q < 64; ++q) {
      float4 wv = wrow[q];
      float4 hh = ((const float4*)sHF)[q];
      a += wv.x * hh.x + wv.y * hh.y + wv.z * hh.z + wv.w * hh.w;
    }
    out[(size_t)b * 128 + v] = a;
  }
}

extern "C" void kernel_launch(void* const* d_in, const int* in_sizes, int n_in,
                              void* d_out, int out_size, void* d_ws,
                              size_t ws_size, hipStream_t stream) {
  const float* x    = (const float*)d_in[0];
  // d_in[1] = input_lengths: unused by the reference
  const float* W_ih = (const float*)d_in[2];
  const float* W_hh = (const float*)d_in[3];
  const float* b_ih = (const float*)d_in[4];
  const float* b_hh = (const float*)d_in[5];
  // d_in[6] = W_xi, d_in[7] = b_xi: dead code in the reference
  const float* W_fc = (const float*)d_in[8];
  const float* b_fc = (const float*)d_in[9];
  unsigned char* ws = (unsigned char*)d_ws;

  if (ws_size < WS_NEED) return;  // signature: output stays poisoned

  prep_w<<<512, 256, 0, stream>>>(W_hh, ws);
  prep_p<<<1024, 256, 0, stream>>>(x, W_ih, b_ih, b_hh, ws);
  scan_k<<<128, 512, 0, stream>>>(ws, W_fc, b_fc, (float*)d_out);
}